// Round 2
// baseline (403.297 us; speedup 1.0000x reference)
//
#include <hip/hip_runtime.h>
#include <hip/hip_bf16.h>
#include <stdint.h>

typedef __attribute__((ext_vector_type(8))) short bf16x8;
typedef __attribute__((ext_vector_type(4))) float f32x4;

__device__ __forceinline__ unsigned short f2bf(float f) {
    union { float f; unsigned u; } v; v.f = f;
    unsigned u = v.u;
    u += 0x7fff + ((u >> 16) & 1);   // round-to-nearest-even
    return (unsigned short)(u >> 16);
}

__device__ __forceinline__ bf16x8 pack_bf8(float4 a, float4 b) {
    bf16x8 r;
    r[0]=(short)f2bf(a.x); r[1]=(short)f2bf(a.y); r[2]=(short)f2bf(a.z); r[3]=(short)f2bf(a.w);
    r[4]=(short)f2bf(b.x); r[5]=(short)f2bf(b.y); r[6]=(short)f2bf(b.z); r[7]=(short)f2bf(b.w);
    return r;
}

// ---------------------------------------------------------------------------
// Prep: convert queries + W0..W3 (fp32) -> bf16 in workspace.
// ---------------------------------------------------------------------------
__global__ __launch_bounds__(256) void prep_convert(
    const float* __restrict__ q, const float* __restrict__ W0,
    const float* __restrict__ W1, const float* __restrict__ W2,
    const float* __restrict__ W3,
    unsigned short* __restrict__ wsQ, unsigned short* __restrict__ wsW,
    int nq_elems, int wsz)
{
    int idx = (blockIdx.x * 256 + threadIdx.x) * 4;
    int total = nq_elems + 4 * wsz;
    if (idx >= total) return;
    const float* src; unsigned short* dst;
    if (idx < nq_elems) { src = q + idx; dst = wsQ + idx; }
    else {
        int r = idx - nq_elems;
        int l = r / wsz, off = r - l * wsz;
        const float* Ws = (l == 0) ? W0 : (l == 1) ? W1 : (l == 2) ? W2 : W3;
        src = Ws + off; dst = wsW + (size_t)l * wsz + off;
    }
    float4 v = *(const float4*)src;
    ushort4 o;
    o.x = f2bf(v.x); o.y = f2bf(v.y); o.z = f2bf(v.z); o.w = f2bf(v.w);
    *(ushort4*)dst = o;
}

// ---------------------------------------------------------------------------
// Fused 4-layer MLP. Block = 16 query rows x all 256 N. A-tile ping-pongs
// through LDS between layers; W read as bf16 fragments straight from L2.
// ---------------------------------------------------------------------------
__global__ __launch_bounds__(256) void mlp_fused(
    const unsigned short* __restrict__ Qb,    // wsQ (M,256) bf16
    const unsigned short* __restrict__ Wb,    // wsW 4x(256,256) bf16 (n,k)
    const float* __restrict__ b0p, const float* __restrict__ b1p,
    const float* __restrict__ b2p, const float* __restrict__ b3p,
    unsigned short* __restrict__ outQB, int M, int wsz)
{
    __shared__ unsigned short At[16 * 264];
    const int tid = threadIdx.x;
    const int m0 = blockIdx.x * 16;
    const int wid = tid >> 6, lane = tid & 63, quad = lane >> 4, l16 = lane & 15;

    // stage initial A tile (bf16 queries)
    #pragma unroll
    for (int i = 0; i < 2; ++i) {
        int c = tid + i * 256;            // 512 chunks of 8 bf16
        int row = c >> 5, col = (c & 31) * 8;
        int gr = m0 + row; if (gr >= M) gr = M - 1;
        uint4 v = *(const uint4*)(Qb + (size_t)gr * 256 + col);
        *(uint4*)&At[row * 264 + col] = v;
    }
    __syncthreads();

    for (int l = 0; l < 4; ++l) {
        const unsigned short* Wl = Wb + (size_t)l * wsz;
        const float* bl = (l == 0) ? b0p : (l == 1) ? b1p : (l == 2) ? b2p : b3p;
        f32x4 acc[4] = {};
        #pragma unroll
        for (int k = 0; k < 256; k += 32) {
            bf16x8 af = *(const bf16x8*)&At[l16 * 264 + k + quad * 8];
            #pragma unroll
            for (int t = 0; t < 4; ++t) {
                int n = wid * 64 + t * 16 + l16;
                bf16x8 bf = *(const bf16x8*)(Wl + (size_t)n * 256 + k + quad * 8);
                acc[t] = __builtin_amdgcn_mfma_f32_16x16x32_bf16(af, bf, acc[t], 0, 0, 0);
            }
        }
        __syncthreads();   // all waves done reading At for this layer
        #pragma unroll
        for (int t = 0; t < 4; ++t) {
            int n = wid * 64 + t * 16 + l16;
            float bv = bl[n];
            #pragma unroll
            for (int r = 0; r < 4; ++r) {
                int m = quad * 4 + r;
                float v = acc[t][r] + bv;
                if (l < 3) {
                    v = fmaxf(v, 0.f);
                    At[m * 264 + n] = f2bf(v);
                } else {
                    if (m0 + m < M) outQB[(size_t)(m0 + m) * 256 + n] = f2bf(v);
                }
            }
        }
        if (l < 3) __syncthreads();
    }
}

// ---------------------------------------------------------------------------
// Cell-owner fused gather + GEMM + store. Block owns 32 output cells of one
// batch: scan FI for matching features, LDS-accumulate FV rows, then
// (32x256) x (256xQ) bf16 MFMA GEMM, plain coalesced stores. NO global
// atomics, NO memset (every out element written exactly once).
// ---------------------------------------------------------------------------
__global__ __launch_bounds__(256) void cell_gemm(
    const float* __restrict__ FV, const int* __restrict__ FI,
    const unsigned short* __restrict__ QB, const int* __restrict__ qoff,
    const int* __restrict__ foff, const int* __restrict__ wptr,
    float* __restrict__ out, int bpb, int HW, int Qstride)
{
    __shared__ float cellAcc[32 * 260];        // 33280 B, pad 260 => conflict-free
    __shared__ unsigned short Bsm[304 * 40];   // 24320 B, pad 40  => conflict-free
    __shared__ int list[1024];
    __shared__ int cnt;

    const int tid = threadIdx.x;
    const int bid = blockIdx.x;
    const int b   = bid / bpb;
    const int c0  = (bid - b * bpb) * 32;
    const int Wd  = *wptr;
    const int f0 = foff[b], f1 = foff[b + 1];
    const int q0 = qoff[b], qlen = qoff[b + 1] - q0;

    if (tid == 0) cnt = 0;
    for (int c = tid; c < 32 * 260; c += 256) cellAcc[c] = 0.f;
    __syncthreads();

    // ---- scan features of this batch for cells in [c0, c0+32) ----
    for (int i = f0 + tid; i < f1; i += 256) {
        int h = FI[(size_t)i * 3 + 1];
        int w = FI[(size_t)i * 3 + 2];
        unsigned cl = (unsigned)(h * Wd + w - c0);
        if (cl < 32u) {
            int pos = atomicAdd(&cnt, 1);
            if (pos < 1024) {
                list[pos] = (int)((cl << 27) | (unsigned)i);
            } else {
                // overflow fallback (statistically unreachable): serial LDS adds
                for (int k = 0; k < 256; ++k)
                    atomicAdd(&cellAcc[cl * 260 + k], FV[(size_t)i * 256 + k]);
            }
        }
    }
    __syncthreads();

    // ---- accumulate matched FV rows into LDS (64 lanes per row) ----
    const int lane = tid & 63, wid = tid >> 6;
    int nmatch = cnt; if (nmatch > 1024) nmatch = 1024;
    for (int j = wid; j < nmatch; j += 4) {
        int e = list[j];
        int cl = ((unsigned)e) >> 27;
        int i  = e & 0x07ffffff;
        const float* src = FV + (size_t)i * 256;
        float v0 = src[lane], v1 = src[lane + 64], v2 = src[lane + 128], v3 = src[lane + 192];
        atomicAdd(&cellAcc[cl * 260 + lane],       v0);
        atomicAdd(&cellAcc[cl * 260 + lane + 64],  v1);
        atomicAdd(&cellAcc[cl * 260 + lane + 128], v2);
        atomicAdd(&cellAcc[cl * 260 + lane + 192], v3);
    }
    __syncthreads();

    // ---- GEMM: A = cellAcc (32x256), B = QB rows q0..q0+qlen ----
    const int quad = lane >> 4, l16 = lane & 15;
    const int rowbase = (wid >> 1) * 16;           // waves {0,1}->rows 0..15, {2,3}->16..31
    const int t0 = (wid & 1) * 10;                 // even waves tiles 0..9, odd 10..18
    const int ntiles = (wid & 1) ? 9 : 10;
    f32x4 acc[10] = {};

    for (int k0 = 0; k0 < 256; k0 += 32) {
        // stage B tile: 304 q-rows x 32 k (bf16), padded stride 40
        for (int c = tid; c < 1216; c += 256) {
            int row = c >> 2;
            int kc  = (c & 3) * 8;
            int qrow = row < qlen ? row : qlen - 1;
            uint4 v = *(const uint4*)(QB + (size_t)(q0 + qrow) * 256 + k0 + kc);
            *(uint4*)&Bsm[row * 40 + kc] = v;
        }
        // A fragment from LDS (disjoint region; no barrier needed before)
        float4 a0 = *(const float4*)&cellAcc[(rowbase + l16) * 260 + k0 + quad * 8];
        float4 a1 = *(const float4*)&cellAcc[(rowbase + l16) * 260 + k0 + quad * 8 + 4];
        bf16x8 af = pack_bf8(a0, a1);
        __syncthreads();
        #pragma unroll
        for (int t = 0; t < 10; ++t) {
            if (t < ntiles) {
                bf16x8 bf = *(const bf16x8*)&Bsm[((t0 + t) * 16 + l16) * 40 + quad * 8];
                acc[t] = __builtin_amdgcn_mfma_f32_16x16x32_bf16(af, bf, acc[t], 0, 0, 0);
            }
        }
        __syncthreads();
    }

    // ---- plain coalesced stores (each out element written exactly once) ----
    #pragma unroll
    for (int r = 0; r < 4; ++r) {
        int m = quad * 4 + r;
        float* dst = out + ((size_t)b * HW + c0 + rowbase + m) * Qstride;
        #pragma unroll
        for (int t = 0; t < 10; ++t) {
            if (t < ntiles) {
                int nq = (t0 + t) * 16 + l16;
                if (nq < Qstride) {
                    float v = (nq < qlen) ? acc[t][r] : 0.f;
                    dst[nq] = v;
                }
            }
        }
    }
}

extern "C" void kernel_launch(void* const* d_in, const int* in_sizes, int n_in,
                              void* d_out, int out_size, void* d_ws, size_t ws_size,
                              hipStream_t stream) {
    const float* queries = (const float*)d_in[0];
    const float* FV      = (const float*)d_in[1];
    const int*   FI      = (const int*)d_in[2];
    const int*   qoff    = (const int*)d_in[3];
    const int*   foff    = (const int*)d_in[4];
    const int*   wptr    = (const int*)d_in[6];
    const float* W0 = (const float*)d_in[7];
    const float* b0 = (const float*)d_in[8];
    const float* W1 = (const float*)d_in[9];
    const float* b1 = (const float*)d_in[10];
    const float* W2 = (const float*)d_in[11];
    const float* b2 = (const float*)d_in[12];
    const float* W3 = (const float*)d_in[13];
    const float* b3 = (const float*)d_in[14];
    float* out = (float*)d_out;

    const int NQe = in_sizes[0];          // 307200
    const int NQ  = NQe / 256;            // 1200
    const int WSZ = in_sizes[7];          // 65536
    const int B   = in_sizes[3] - 1;      // 4
    const int Q   = NQ / B;               // 300 (uniform lengths => Qm == Q)
    const int HW  = out_size / (B * Q);   // 16384
    const int bpb = HW / 32;              // blocks per batch
    const int Qstride = Q;

    unsigned short* wsW  = (unsigned short*)d_ws;                 // 4*WSZ bf16
    unsigned short* wsQ  = wsW + (size_t)4 * WSZ;                 // NQe bf16
    unsigned short* wsQB = wsQ + (size_t)NQe;                     // NQe bf16

    int prep_total = NQe + 4 * WSZ;
    int prep_grid  = (prep_total / 4 + 255) / 256;
    prep_convert<<<prep_grid, 256, 0, stream>>>(queries, W0, W1, W2, W3,
                                                wsQ, wsW, NQe, WSZ);

    mlp_fused<<<(NQ + 15) / 16, 256, 0, stream>>>(wsQ, wsW, b0, b1, b2, b3,
                                                  wsQB, NQ, WSZ);

    cell_gemm<<<B * bpb, 256, 0, stream>>>(FV, FI, wsQB, qoff, foff, wptr,
                                           out, bpb, HW, Qstride);
}

// Round 3
// 284.483 us; speedup vs baseline: 1.4177x; 1.4177x over previous
//
#include <hip/hip_runtime.h>
#include <hip/hip_bf16.h>
#include <stdint.h>

typedef __attribute__((ext_vector_type(8))) short bf16x8;
typedef __attribute__((ext_vector_type(4))) float f32x4;

__device__ __forceinline__ unsigned short f2bf(float f) {
    union { float f; unsigned u; } v; v.f = f;
    unsigned u = v.u;
    u += 0x7fff + ((u >> 16) & 1);   // round-to-nearest-even
    return (unsigned short)(u >> 16);
}

__device__ __forceinline__ bf16x8 pack_bf8(float4 a, float4 b) {
    bf16x8 r;
    r[0]=(short)f2bf(a.x); r[1]=(short)f2bf(a.y); r[2]=(short)f2bf(a.z); r[3]=(short)f2bf(a.w);
    r[4]=(short)f2bf(b.x); r[5]=(short)f2bf(b.y); r[6]=(short)f2bf(b.z); r[7]=(short)f2bf(b.w);
    return r;
}

// ---------------------------------------------------------------------------
// Global binning: one thread per feature claims a slot in its cell's list.
// 65536 int atomics total (~256x fewer atomic ops than scatter-adding rows).
// Slot cap 16: P(Poisson(1) >= 17) * 65536 cells ~ 3e-9 -> drop risk nil.
// ---------------------------------------------------------------------------
__global__ __launch_bounds__(256) void binner(
    const int* __restrict__ FI, const int* __restrict__ wptr,
    int* __restrict__ cnt, int* __restrict__ slots, int NF, int HW)
{
    int i = blockIdx.x * 256 + threadIdx.x;
    if (i >= NF) return;
    int Wd = *wptr;
    int b = FI[(size_t)i * 3];
    int h = FI[(size_t)i * 3 + 1];
    int w = FI[(size_t)i * 3 + 2];
    int gc = b * HW + h * Wd + w;
    int slot = atomicAdd(&cnt[gc], 1);
    if (slot < 16) slots[(size_t)gc * 16 + slot] = i;
}

// ---------------------------------------------------------------------------
// Fused 4-layer MLP, fp32 inputs converted inline (no prep kernel).
// Block = 16 query rows x all 256 N; A-tile ping-pongs through LDS.
// ---------------------------------------------------------------------------
__global__ __launch_bounds__(256) void mlp_fused(
    const float* __restrict__ Qf,
    const float* __restrict__ W0, const float* __restrict__ W1,
    const float* __restrict__ W2, const float* __restrict__ W3,
    const float* __restrict__ b0p, const float* __restrict__ b1p,
    const float* __restrict__ b2p, const float* __restrict__ b3p,
    unsigned short* __restrict__ outQB, int M)
{
    __shared__ unsigned short At[16 * 264];
    const int tid = threadIdx.x;
    const int m0 = blockIdx.x * 16;
    const int wid = tid >> 6, lane = tid & 63, quad = lane >> 4, l16 = lane & 15;

    // stage A tile: 16x256 fp32 -> bf16 (1024 float4 chunks, 4/thread)
    #pragma unroll
    for (int i = 0; i < 4; ++i) {
        int c = tid + i * 256;
        int row = c >> 6, kq = (c & 63) * 4;
        int gr = m0 + row; if (gr >= M) gr = M - 1;
        float4 v = *(const float4*)(Qf + (size_t)gr * 256 + kq);
        ushort4 o; o.x = f2bf(v.x); o.y = f2bf(v.y); o.z = f2bf(v.z); o.w = f2bf(v.w);
        *(ushort4*)&At[row * 264 + kq] = o;
    }
    __syncthreads();

    for (int l = 0; l < 4; ++l) {
        const float* Wl = (l == 0) ? W0 : (l == 1) ? W1 : (l == 2) ? W2 : W3;
        const float* bl = (l == 0) ? b0p : (l == 1) ? b1p : (l == 2) ? b2p : b3p;
        f32x4 acc[4] = {};
        #pragma unroll
        for (int k = 0; k < 256; k += 32) {
            bf16x8 af = *(const bf16x8*)&At[l16 * 264 + k + quad * 8];
            #pragma unroll
            for (int t = 0; t < 4; ++t) {
                int n = wid * 64 + t * 16 + l16;
                const float* wp = Wl + (size_t)n * 256 + k + quad * 8;
                float4 wa = *(const float4*)wp;
                float4 wb = *(const float4*)(wp + 4);
                bf16x8 bf = pack_bf8(wa, wb);
                acc[t] = __builtin_amdgcn_mfma_f32_16x16x32_bf16(af, bf, acc[t], 0, 0, 0);
            }
        }
        __syncthreads();   // all waves done reading At for this layer
        #pragma unroll
        for (int t = 0; t < 4; ++t) {
            int n = wid * 64 + t * 16 + l16;
            float bv = bl[n];
            #pragma unroll
            for (int r = 0; r < 4; ++r) {
                int m = quad * 4 + r;
                float v = acc[t][r] + bv;
                if (l < 3) {
                    At[m * 264 + n] = f2bf(fmaxf(v, 0.f));
                } else {
                    if (m0 + m < M) outQB[(size_t)(m0 + m) * 256 + n] = f2bf(v);
                }
            }
        }
        if (l < 3) __syncthreads();
    }
}

// ---------------------------------------------------------------------------
// Cell-owner gather + GEMM + store, NO per-block scan: per-cell feature
// lists come from the binner. Block = 64 cells x 304 queries, K=256.
// A staged once (wave-local rows, no cross-wave dependency); B in BK=32
// chunks. No global atomics, no memset: every out element stored once.
// ---------------------------------------------------------------------------
__global__ __launch_bounds__(256) void cell_gemm(
    const float* __restrict__ FV, const int* __restrict__ cnt,
    const int* __restrict__ slots, const unsigned short* __restrict__ QB,
    const int* __restrict__ qoff, float* __restrict__ out,
    int cpb, int HW, int Qstride)
{
    __shared__ unsigned short Asm2[64 * 264];   // 33792 B
    __shared__ unsigned short Bsm[304 * 40];    // 24320 B
    __shared__ int scnt[64];
    __shared__ int sslot[64 * 16];              // 4096 B   (total 62464 B)

    const int tid = threadIdx.x;
    const int b   = blockIdx.x / cpb;
    const int c0  = (blockIdx.x - b * cpb) * 64;
    const int gc0 = b * HW + c0;
    const int q0 = qoff[b], qlen = qoff[b + 1] - q0;

    // prefetch this block's counters + slot lists (coalesced)
    if (tid < 64) scnt[tid] = cnt[gc0 + tid];
    #pragma unroll
    for (int i = 0; i < 4; ++i)
        sslot[tid + i * 256] = slots[(size_t)gc0 * 16 + tid + i * 256];
    __syncthreads();

    const int wid = tid >> 6, lane = tid & 63, quad = lane >> 4, l16 = lane & 15;

    // gather: wave `wid` owns cells wid*16 .. wid*16+15 (rows it will read)
    for (int j = 0; j < 16; ++j) {
        int cl = wid * 16 + j;
        int n = scnt[cl]; if (n > 16) n = 16;
        float4 a = make_float4(0.f, 0.f, 0.f, 0.f);
        for (int s = 0; s < n; ++s) {
            int f = sslot[cl * 16 + s];
            float4 v = *(const float4*)(FV + (size_t)f * 256 + lane * 4);
            a.x += v.x; a.y += v.y; a.z += v.z; a.w += v.w;
        }
        ushort4 o; o.x = f2bf(a.x); o.y = f2bf(a.y); o.z = f2bf(a.z); o.w = f2bf(a.w);
        *(ushort4*)&Asm2[cl * 264 + lane * 4] = o;
    }
    // A rows are wave-local (wave w writes and reads rows w*16..w*16+15),
    // so no barrier needed for A; Bsm barrier below also fences LDS.

    f32x4 acc[19] = {};
    for (int k0 = 0; k0 < 256; k0 += 32) {
        // stage B: 304 q-rows x 32 k bf16, padded stride 40 (conflict-free)
        for (int c = tid; c < 1216; c += 256) {
            int row = c >> 2, kc = (c & 3) * 8;
            int qr = row < qlen ? row : qlen - 1;
            uint4 v = *(const uint4*)(QB + (size_t)(q0 + qr) * 256 + k0 + kc);
            *(uint4*)&Bsm[row * 40 + kc] = v;
        }
        __syncthreads();
        bf16x8 af = *(const bf16x8*)&Asm2[(wid * 16 + l16) * 264 + k0 + quad * 8];
        #pragma unroll
        for (int t = 0; t < 19; ++t) {
            bf16x8 bf = *(const bf16x8*)&Bsm[(t * 16 + l16) * 40 + quad * 8];
            acc[t] = __builtin_amdgcn_mfma_f32_16x16x32_bf16(af, bf, acc[t], 0, 0, 0);
        }
        __syncthreads();
    }

    // coalesced stores; zero-fill n >= qlen so no memset is needed
    #pragma unroll
    for (int r = 0; r < 4; ++r) {
        int m = quad * 4 + r;
        float* dst = out + ((size_t)b * HW + c0 + wid * 16 + m) * Qstride;
        #pragma unroll
        for (int t = 0; t < 19; ++t) {
            int nq = t * 16 + l16;
            if (nq < Qstride) dst[nq] = (nq < qlen) ? acc[t][r] : 0.f;
        }
    }
}

extern "C" void kernel_launch(void* const* d_in, const int* in_sizes, int n_in,
                              void* d_out, int out_size, void* d_ws, size_t ws_size,
                              hipStream_t stream) {
    const float* queries = (const float*)d_in[0];
    const float* FV      = (const float*)d_in[1];
    const int*   FI      = (const int*)d_in[2];
    const int*   qoff    = (const int*)d_in[3];
    const int*   wptr    = (const int*)d_in[6];
    const float* W0 = (const float*)d_in[7];
    const float* b0 = (const float*)d_in[8];
    const float* W1 = (const float*)d_in[9];
    const float* b1 = (const float*)d_in[10];
    const float* W2 = (const float*)d_in[11];
    const float* b2 = (const float*)d_in[12];
    const float* W3 = (const float*)d_in[13];
    const float* b3 = (const float*)d_in[14];
    float* out = (float*)d_out;

    const int NQe = in_sizes[0];          // 307200
    const int NQ  = NQe / 256;            // 1200
    const int NF  = in_sizes[1] / 256;    // 65536
    const int B   = in_sizes[3] - 1;      // 4
    const int Q   = NQ / B;               // 300
    const int HW  = out_size / (B * Q);   // 16384
    const int cpb = HW / 64;              // 256 blocks per batch

    int* cnt   = (int*)d_ws;                                  // B*HW ints
    int* slots = cnt + (size_t)B * HW;                        // B*HW*16 ints
    unsigned short* wsQB = (unsigned short*)(slots + (size_t)B * HW * 16);

    hipMemsetAsync(cnt, 0, (size_t)B * HW * sizeof(int), stream);

    binner<<<(NF + 255) / 256, 256, 0, stream>>>(FI, wptr, cnt, slots, NF, HW);

    mlp_fused<<<(NQ + 15) / 16, 256, 0, stream>>>(queries, W0, W1, W2, W3,
                                                  b0, b1, b2, b3, wsQB, NQ);

    cell_gemm<<<B * cpb, 256, 0, stream>>>(FV, cnt, slots, wsQB, qoff,
                                           out, cpb, HW, Q);
}

// Round 4
// 248.693 us; speedup vs baseline: 1.6217x; 1.1439x over previous
//
#include <hip/hip_runtime.h>
#include <hip/hip_bf16.h>
#include <stdint.h>

typedef __attribute__((ext_vector_type(8))) short bf16x8;
typedef __attribute__((ext_vector_type(4))) float f32x4;

__device__ __forceinline__ unsigned short f2bf(float f) {
    union { float f; unsigned u; } v; v.f = f;
    unsigned u = v.u;
    u += 0x7fff + ((u >> 16) & 1);   // round-to-nearest-even
    return (unsigned short)(u >> 16);
}

// ---------------------------------------------------------------------------
// prep: blocks [0, nbBin): binner (slot claim per feature).
//       blocks [nbBin, nbBin+nbW): convert W0..W3 fp32 -> bf16 into wsW.
// ---------------------------------------------------------------------------
__global__ __launch_bounds__(256) void prep(
    const int* __restrict__ FI, const int* __restrict__ wptr,
    int* __restrict__ cnt, int* __restrict__ slots,
    const float* __restrict__ W0, const float* __restrict__ W1,
    const float* __restrict__ W2, const float* __restrict__ W3,
    unsigned short* __restrict__ wsW,
    int NF, int HW, int wsz, int nbBin)
{
    int blk = blockIdx.x;
    if (blk < nbBin) {
        int i = blk * 256 + threadIdx.x;
        if (i >= NF) return;
        int Wd = *wptr;
        int b = FI[(size_t)i * 3];
        int h = FI[(size_t)i * 3 + 1];
        int w = FI[(size_t)i * 3 + 2];
        int gc = b * HW + h * Wd + w;
        int slot = atomicAdd(&cnt[gc], 1);
        if (slot < 16) slots[(size_t)gc * 16 + slot] = i;
    } else {
        int idx = ((blk - nbBin) * 256 + threadIdx.x) * 4;   // element index
        if (idx >= 4 * wsz) return;
        int l = idx / wsz, off = idx - l * wsz;
        const float* Ws = (l == 0) ? W0 : (l == 1) ? W1 : (l == 2) ? W2 : W3;
        float4 v = *(const float4*)(Ws + off);
        ushort4 o; o.x = f2bf(v.x); o.y = f2bf(v.y); o.z = f2bf(v.z); o.w = f2bf(v.w);
        *(ushort4*)(wsW + (size_t)l * wsz + off) = o;
    }
}

// ---------------------------------------------------------------------------
// Fused 4-layer MLP; W pre-converted bf16 (one 16B load per B-fragment).
// Block = 16 query rows x all 256 N; A-tile ping-pongs through LDS.
// ---------------------------------------------------------------------------
__global__ __launch_bounds__(256) void mlp_fused(
    const float* __restrict__ Qf, const unsigned short* __restrict__ Wb,
    const float* __restrict__ b0p, const float* __restrict__ b1p,
    const float* __restrict__ b2p, const float* __restrict__ b3p,
    unsigned short* __restrict__ outQB, int M, int wsz)
{
    __shared__ unsigned short At[16 * 264];
    const int tid = threadIdx.x;
    const int m0 = blockIdx.x * 16;
    const int wid = tid >> 6, lane = tid & 63, quad = lane >> 4, l16 = lane & 15;

    // stage A tile: 16x256 fp32 -> bf16 (1024 float4 chunks, 4/thread)
    #pragma unroll
    for (int i = 0; i < 4; ++i) {
        int c = tid + i * 256;
        int row = c >> 6, kq = (c & 63) * 4;
        int gr = m0 + row; if (gr >= M) gr = M - 1;
        float4 v = *(const float4*)(Qf + (size_t)gr * 256 + kq);
        ushort4 o; o.x = f2bf(v.x); o.y = f2bf(v.y); o.z = f2bf(v.z); o.w = f2bf(v.w);
        *(ushort4*)&At[row * 264 + kq] = o;
    }
    __syncthreads();

    for (int l = 0; l < 4; ++l) {
        const unsigned short* Wl = Wb + (size_t)l * wsz;
        const float* bl = (l == 0) ? b0p : (l == 1) ? b1p : (l == 2) ? b2p : b3p;
        f32x4 acc[4] = {};
        #pragma unroll
        for (int k = 0; k < 256; k += 32) {
            bf16x8 af = *(const bf16x8*)&At[l16 * 264 + k + quad * 8];
            #pragma unroll
            for (int t = 0; t < 4; ++t) {
                int n = wid * 64 + t * 16 + l16;
                bf16x8 bfr = *(const bf16x8*)(Wl + (size_t)n * 256 + k + quad * 8);
                acc[t] = __builtin_amdgcn_mfma_f32_16x16x32_bf16(af, bfr, acc[t], 0, 0, 0);
            }
        }
        __syncthreads();
        #pragma unroll
        for (int t = 0; t < 4; ++t) {
            int n = wid * 64 + t * 16 + l16;
            float bv = bl[n];
            #pragma unroll
            for (int r = 0; r < 4; ++r) {
                int m = quad * 4 + r;
                float v = acc[t][r] + bv;
                if (l < 3) {
                    At[m * 264 + n] = f2bf(fmaxf(v, 0.f));
                } else {
                    if (m0 + m < M) outQB[(size_t)(m0 + m) * 256 + n] = f2bf(v);
                }
            }
        }
        if (l < 3) __syncthreads();
    }
}

// ---------------------------------------------------------------------------
// gather_cells: wave-per-cell; sum slotted FV rows, write bf16 A row.
// No LDS, tiny VGPR -> high occupancy, pure memory streaming.
// ---------------------------------------------------------------------------
__global__ __launch_bounds__(256) void gather_cells(
    const float* __restrict__ FV, const int* __restrict__ cnt,
    const int* __restrict__ slots, unsigned short* __restrict__ Abuf, int NC)
{
    const int wid = threadIdx.x >> 6, lane = threadIdx.x & 63;
    const int wg = blockIdx.x * 4 + wid;
    const int nw = gridDim.x * 4;
    for (int c = wg; c < NC; c += nw) {
        int n = cnt[c]; if (n > 16) n = 16;
        int sl = (lane < 16) ? slots[(size_t)c * 16 + lane] : 0;
        float4 a = make_float4(0.f, 0.f, 0.f, 0.f);
        for (int s = 0; s < n; ++s) {
            int f = __shfl(sl, s);
            float4 v = *(const float4*)(FV + (size_t)f * 256 + lane * 4);
            a.x += v.x; a.y += v.y; a.z += v.z; a.w += v.w;
        }
        ushort4 o; o.x = f2bf(a.x); o.y = f2bf(a.y); o.z = f2bf(a.z); o.w = f2bf(a.w);
        *(ushort4*)&Abuf[(size_t)c * 256 + lane * 4] = o;
    }
}

// ---------------------------------------------------------------------------
// cell_gemm2: pure GEMM. A (64 cells x 256) staged once from contiguous
// bf16; B (304 q x BK=32) staged per k-step; MFMA; coalesced stores.
// No atomics, no memset (every out element stored exactly once).
// ---------------------------------------------------------------------------
__global__ __launch_bounds__(256, 2) void cell_gemm2(
    const unsigned short* __restrict__ Abuf,
    const unsigned short* __restrict__ QB, const int* __restrict__ qoff,
    float* __restrict__ out, int cpb, int HW, int Qstride)
{
    __shared__ unsigned short Asm[64 * 264];   // 33792 B
    __shared__ unsigned short Bsm[304 * 40];   // 24320 B

    const int tid = threadIdx.x;
    const int b   = blockIdx.x / cpb;
    const int c0  = (blockIdx.x - b * cpb) * 64;
    const size_t gc0 = (size_t)b * HW + c0;
    const int q0 = qoff[b];
    int qlen = qoff[b + 1] - q0; if (qlen < 1) qlen = 1;

    const int wid = tid >> 6, lane = tid & 63, quad = lane >> 4, l16 = lane & 15;

    // stage A once: 64 rows x 256 bf16 = 2048 uint4 chunks, 8/thread
    #pragma unroll
    for (int i = 0; i < 8; ++i) {
        int c = tid + i * 256;
        int row = c >> 5, ch = (c & 31) * 8;
        uint4 v = *(const uint4*)(Abuf + (gc0 + row) * 256 + ch);
        *(uint4*)&Asm[row * 264 + ch] = v;
    }

    f32x4 acc[19] = {};
    for (int k0 = 0; k0 < 256; k0 += 32) {
        // stage B: 304 q-rows x 32 k bf16, padded stride 40 (conflict-free)
        for (int c = tid; c < 1216; c += 256) {
            int row = c >> 2, kc = (c & 3) * 8;
            int qr = row < qlen ? row : qlen - 1;
            uint4 v = *(const uint4*)(QB + (size_t)(q0 + qr) * 256 + k0 + kc);
            *(uint4*)&Bsm[row * 40 + kc] = v;
        }
        __syncthreads();
        bf16x8 af = *(const bf16x8*)&Asm[(wid * 16 + l16) * 264 + k0 + quad * 8];
        #pragma unroll
        for (int t = 0; t < 19; ++t) {
            bf16x8 bfr = *(const bf16x8*)&Bsm[(t * 16 + l16) * 40 + quad * 8];
            acc[t] = __builtin_amdgcn_mfma_f32_16x16x32_bf16(af, bfr, acc[t], 0, 0, 0);
        }
        __syncthreads();
    }

    // coalesced stores; zero-fill n >= qlen (no memset of d_out needed)
    #pragma unroll
    for (int r = 0; r < 4; ++r) {
        int m = quad * 4 + r;
        float* dst = out + (gc0 + wid * 16 + m) * Qstride;
        #pragma unroll
        for (int t = 0; t < 19; ++t) {
            int nq = t * 16 + l16;
            if (nq < Qstride) dst[nq] = (nq < qlen) ? acc[t][r] : 0.f;
        }
    }
}

extern "C" void kernel_launch(void* const* d_in, const int* in_sizes, int n_in,
                              void* d_out, int out_size, void* d_ws, size_t ws_size,
                              hipStream_t stream) {
    const float* queries = (const float*)d_in[0];
    const float* FV      = (const float*)d_in[1];
    const int*   FI      = (const int*)d_in[2];
    const int*   qoff    = (const int*)d_in[3];
    const int*   wptr    = (const int*)d_in[6];
    const float* W0 = (const float*)d_in[7];
    const float* b0 = (const float*)d_in[8];
    const float* W1 = (const float*)d_in[9];
    const float* b1 = (const float*)d_in[10];
    const float* W2 = (const float*)d_in[11];
    const float* b2 = (const float*)d_in[12];
    const float* W3 = (const float*)d_in[13];
    const float* b3 = (const float*)d_in[14];
    float* out = (float*)d_out;

    const int NQe = in_sizes[0];          // 307200
    const int NQ  = NQe / 256;            // 1200
    const int NF  = in_sizes[1] / 256;    // 65536
    const int WSZ = in_sizes[7];          // 65536
    const int B   = in_sizes[3] - 1;      // 4
    const int Q   = NQ / B;               // 300
    const int HW  = out_size / (B * Q);   // 16384
    const int NC  = B * HW;               // 65536 cells
    const int cpb = HW / 64;              // 256 blocks per batch

    int* cnt   = (int*)d_ws;                                   // NC ints
    int* slots = cnt + (size_t)NC;                             // NC*16 ints
    unsigned short* wsW  = (unsigned short*)(slots + (size_t)NC * 16);  // 4*WSZ
    unsigned short* wsQB = wsW + (size_t)4 * WSZ;              // NQe bf16
    unsigned short* Abuf = wsQB + (size_t)NQe;                 // NC*256 bf16

    hipMemsetAsync(cnt, 0, (size_t)NC * sizeof(int), stream);

    const int nbBin = (NF + 255) / 256;
    const int nbW   = (4 * WSZ / 4 + 255) / 256;
    prep<<<nbBin + nbW, 256, 0, stream>>>(FI, wptr, cnt, slots,
                                          W0, W1, W2, W3, wsW, NF, HW, WSZ, nbBin);

    mlp_fused<<<(NQ + 15) / 16, 256, 0, stream>>>(queries, wsW, b0, b1, b2, b3,
                                                  wsQB, NQ, WSZ);

    gather_cells<<<1024, 256, 0, stream>>>(FV, cnt, slots, Abuf, NC);

    cell_gemm2<<<B * cpb, 256, 0, stream>>>(Abuf, wsQB, qoff, out, cpb, HW, Q);
}

// Round 5
// 215.941 us; speedup vs baseline: 1.8676x; 1.1517x over previous
//
#include <hip/hip_runtime.h>
#include <hip/hip_bf16.h>
#include <stdint.h>

typedef __attribute__((ext_vector_type(8))) short bf16x8;
typedef __attribute__((ext_vector_type(4))) float f32x4;

__device__ __forceinline__ unsigned short f2bf(float f) {
    union { float f; unsigned u; } v; v.f = f;
    unsigned u = v.u;
    u += 0x7fff + ((u >> 16) & 1);   // round-to-nearest-even
    return (unsigned short)(u >> 16);
}

// ---------------------------------------------------------------------------
// prep: blocks [0, nbBin): binner (slot claim per feature).
//       blocks [nbBin, nbBin+nbW): convert W0..W3 fp32 -> bf16 into wsW.
// ---------------------------------------------------------------------------
__global__ __launch_bounds__(256) void prep(
    const int* __restrict__ FI, const int* __restrict__ wptr,
    int* __restrict__ cnt, int* __restrict__ slots,
    const float* __restrict__ W0, const float* __restrict__ W1,
    const float* __restrict__ W2, const float* __restrict__ W3,
    unsigned short* __restrict__ wsW,
    int NF, int HW, int wsz, int nbBin)
{
    int blk = blockIdx.x;
    if (blk < nbBin) {
        int i = blk * 256 + threadIdx.x;
        if (i >= NF) return;
        int Wd = *wptr;
        int b = FI[(size_t)i * 3];
        int h = FI[(size_t)i * 3 + 1];
        int w = FI[(size_t)i * 3 + 2];
        int gc = b * HW + h * Wd + w;
        int slot = atomicAdd(&cnt[gc], 1);
        if (slot < 16) slots[(size_t)gc * 16 + slot] = i;
    } else {
        int idx = ((blk - nbBin) * 256 + threadIdx.x) * 4;
        if (idx >= 4 * wsz) return;
        int l = idx / wsz, off = idx - l * wsz;
        const float* Ws = (l == 0) ? W0 : (l == 1) ? W1 : (l == 2) ? W2 : W3;
        float4 v = *(const float4*)(Ws + off);
        ushort4 o; o.x = f2bf(v.x); o.y = f2bf(v.y); o.z = f2bf(v.z); o.w = f2bf(v.w);
        *(ushort4*)(wsW + (size_t)l * wsz + off) = o;
    }
}

// ---------------------------------------------------------------------------
// gather_mlp: blocks [0, nbM): fused 4-layer MLP (latency-bound chain).
//             blocks [nbM, nbM+nbG): cell gather (throughput streaming).
// Independent work fused so MLP latency hides under gather's BW usage.
// ---------------------------------------------------------------------------
__global__ __launch_bounds__(256) void gather_mlp(
    // mlp args
    const float* __restrict__ Qf, const unsigned short* __restrict__ Wb,
    const float* __restrict__ b0p, const float* __restrict__ b1p,
    const float* __restrict__ b2p, const float* __restrict__ b3p,
    unsigned short* __restrict__ outQB, int M, int wsz,
    // gather args
    const float* __restrict__ FV, const int* __restrict__ cnt,
    const int* __restrict__ slots, unsigned short* __restrict__ Abuf, int NC,
    int nbM, int nbG)
{
    __shared__ unsigned short At[16 * 264];
    const int tid = threadIdx.x;
    const int wid = tid >> 6, lane = tid & 63, quad = lane >> 4, l16 = lane & 15;

    if (blockIdx.x >= nbM) {
        // ---------------- gather: wave-per-cell, grid-stride ----------------
        const int wg = (blockIdx.x - nbM) * 4 + wid;
        const int nw = nbG * 4;
        for (int c = wg; c < NC; c += nw) {
            int n = cnt[c]; if (n > 16) n = 16;
            int sl = (lane < 16) ? slots[(size_t)c * 16 + lane] : 0;
            float4 a = make_float4(0.f, 0.f, 0.f, 0.f);
            for (int s = 0; s < n; ++s) {
                int f = __shfl(sl, s);
                float4 v = *(const float4*)(FV + (size_t)f * 256 + lane * 4);
                a.x += v.x; a.y += v.y; a.z += v.z; a.w += v.w;
            }
            ushort4 o; o.x = f2bf(a.x); o.y = f2bf(a.y); o.z = f2bf(a.z); o.w = f2bf(a.w);
            *(ushort4*)&Abuf[(size_t)c * 256 + lane * 4] = o;
        }
        return;
    }

    // ---------------- mlp: 16 query rows x 256 N, LDS ping-pong ----------------
    const int m0 = blockIdx.x * 16;
    #pragma unroll
    for (int i = 0; i < 4; ++i) {
        int c = tid + i * 256;
        int row = c >> 6, kq = (c & 63) * 4;
        int gr = m0 + row; if (gr >= M) gr = M - 1;
        float4 v = *(const float4*)(Qf + (size_t)gr * 256 + kq);
        ushort4 o; o.x = f2bf(v.x); o.y = f2bf(v.y); o.z = f2bf(v.z); o.w = f2bf(v.w);
        *(ushort4*)&At[row * 264 + kq] = o;
    }
    __syncthreads();

    for (int l = 0; l < 4; ++l) {
        const unsigned short* Wl = Wb + (size_t)l * wsz;
        const float* bl = (l == 0) ? b0p : (l == 1) ? b1p : (l == 2) ? b2p : b3p;
        f32x4 acc[4] = {};
        #pragma unroll
        for (int k = 0; k < 256; k += 32) {
            bf16x8 af = *(const bf16x8*)&At[l16 * 264 + k + quad * 8];
            #pragma unroll
            for (int t = 0; t < 4; ++t) {
                int n = wid * 64 + t * 16 + l16;
                bf16x8 bfr = *(const bf16x8*)(Wl + (size_t)n * 256 + k + quad * 8);
                acc[t] = __builtin_amdgcn_mfma_f32_16x16x32_bf16(af, bfr, acc[t], 0, 0, 0);
            }
        }
        __syncthreads();
        #pragma unroll
        for (int t = 0; t < 4; ++t) {
            int n = wid * 64 + t * 16 + l16;
            float bv = bl[n];
            #pragma unroll
            for (int r = 0; r < 4; ++r) {
                int m = quad * 4 + r;
                float v = acc[t][r] + bv;
                if (l < 3) {
                    At[m * 264 + n] = f2bf(fmaxf(v, 0.f));
                } else {
                    if (m0 + m < M) outQB[(size_t)(m0 + m) * 256 + n] = f2bf(v);
                }
            }
        }
        if (l < 3) __syncthreads();
    }
}

// ---------------------------------------------------------------------------
// cell_gemm3: B-only LDS (24.3 KB -> 4 blocks/CU, all 1024 blocks resident).
// A-fragments read per-wave straight from L3-hot Abuf (16B/lane), prefetched
// one K-step ahead. No atomics, no memset.
// ---------------------------------------------------------------------------
__global__ __launch_bounds__(256, 4) void cell_gemm3(
    const unsigned short* __restrict__ Abuf,
    const unsigned short* __restrict__ QB, const int* __restrict__ qoff,
    float* __restrict__ out, int cpb, int HW, int Qstride)
{
    __shared__ unsigned short Bsm[304 * 40];   // 24320 B

    const int tid = threadIdx.x;
    const int b   = blockIdx.x / cpb;
    const int c0  = (blockIdx.x - b * cpb) * 64;
    const size_t gc0 = (size_t)b * HW + c0;
    const int q0 = qoff[b];
    int qlen = qoff[b + 1] - q0; if (qlen < 1) qlen = 1;

    const int wid = tid >> 6, lane = tid & 63, quad = lane >> 4, l16 = lane & 15;

    // A-fragment pointer: row = c0 + wid*16 + l16, col base quad*8
    const unsigned short* aptr = Abuf + (gc0 + wid * 16 + l16) * 256 + quad * 8;
    bf16x8 afA = *(const bf16x8*)aptr;          // k0 = 0 fragment
    f32x4 acc[19] = {};

    for (int k0 = 0; k0 < 256; k0 += 32) {
        // stage B: 304 q-rows x 32 k bf16, padded stride 40
        for (int c = tid; c < 1216; c += 256) {
            int row = c >> 2, kc = (c & 3) * 8;
            int qr = row < qlen ? row : qlen - 1;
            uint4 v = *(const uint4*)(QB + (size_t)(q0 + qr) * 256 + k0 + kc);
            *(uint4*)&Bsm[row * 40 + kc] = v;
        }
        int k1 = (k0 + 32) & 255;               // wraps harmlessly on last iter
        bf16x8 afB = *(const bf16x8*)(aptr + k1);
        __syncthreads();
        #pragma unroll
        for (int t = 0; t < 19; ++t) {
            bf16x8 bfr = *(const bf16x8*)&Bsm[(t * 16 + l16) * 40 + quad * 8];
            acc[t] = __builtin_amdgcn_mfma_f32_16x16x32_bf16(afA, bfr, acc[t], 0, 0, 0);
        }
        __syncthreads();
        afA = afB;
    }

    // coalesced stores; zero-fill n >= qlen (no memset of d_out needed)
    #pragma unroll
    for (int r = 0; r < 4; ++r) {
        int m = quad * 4 + r;
        float* dst = out + (gc0 + wid * 16 + m) * Qstride;
        #pragma unroll
        for (int t = 0; t < 19; ++t) {
            int nq = t * 16 + l16;
            if (nq < Qstride) dst[nq] = (nq < qlen) ? acc[t][r] : 0.f;
        }
    }
}

extern "C" void kernel_launch(void* const* d_in, const int* in_sizes, int n_in,
                              void* d_out, int out_size, void* d_ws, size_t ws_size,
                              hipStream_t stream) {
    const float* queries = (const float*)d_in[0];
    const float* FV      = (const float*)d_in[1];
    const int*   FI      = (const int*)d_in[2];
    const int*   qoff    = (const int*)d_in[3];
    const int*   wptr    = (const int*)d_in[6];
    const float* W0 = (const float*)d_in[7];
    const float* b0 = (const float*)d_in[8];
    const float* W1 = (const float*)d_in[9];
    const float* b1 = (const float*)d_in[10];
    const float* W2 = (const float*)d_in[11];
    const float* b2 = (const float*)d_in[12];
    const float* W3 = (const float*)d_in[13];
    const float* b3 = (const float*)d_in[14];
    float* out = (float*)d_out;

    const int NQe = in_sizes[0];          // 307200
    const int NQ  = NQe / 256;            // 1200
    const int NF  = in_sizes[1] / 256;    // 65536
    const int WSZ = in_sizes[7];          // 65536
    const int B   = in_sizes[3] - 1;      // 4
    const int Q   = NQ / B;               // 300
    const int HW  = out_size / (B * Q);   // 16384
    const int NC  = B * HW;               // 65536 cells
    const int cpb = HW / 64;              // 256 blocks per batch

    int* cnt   = (int*)d_ws;                                   // NC ints
    int* slots = cnt + (size_t)NC;                             // NC*16 ints
    unsigned short* wsW  = (unsigned short*)(slots + (size_t)NC * 16);  // 4*WSZ
    unsigned short* wsQB = wsW + (size_t)4 * WSZ;              // NQe bf16
    unsigned short* Abuf = wsQB + (size_t)NQe;                 // NC*256 bf16

    hipMemsetAsync(cnt, 0, (size_t)NC * sizeof(int), stream);

    const int nbBin = (NF + 255) / 256;
    const int nbW   = (4 * WSZ / 4 + 255) / 256;
    prep<<<nbBin + nbW, 256, 0, stream>>>(FI, wptr, cnt, slots,
                                          W0, W1, W2, W3, wsW, NF, HW, WSZ, nbBin);

    const int nbM = (NQ + 15) / 16;       // 75 mlp blocks
    const int nbG = 1024;                 // gather blocks
    gather_mlp<<<nbM + nbG, 256, 0, stream>>>(
        queries, wsW, b0, b1, b2, b3, wsQB, NQ, WSZ,
        FV, cnt, slots, Abuf, NC, nbM, nbG);

    cell_gemm3<<<B * cpb, 256, 0, stream>>>(Abuf, wsQB, qoff, out, cpb, HW, Q);
}